// Round 9
// baseline (241.547 us; speedup 1.0000x reference)
//
#include <hip/hip_runtime.h>
#include <hip/hip_bf16.h>
#include <cstdint>

// RopelessMLA forward, MI355X/gfx950.
// B=2, S=2048, D=2048, H=16, DH=128, L=512. Outputs: out [2,2048,2048] f32, c_kv [2,2048,512] f32.
//
// Restructuring:
//   K_eff[h,t,dh] = sum_l c_kv[t,l] * absorbed_k[h,dh,l]   (absorb into keys, QK^T K-dim = 128)
//   scores (log2-domain): absorbed_k pre-scaled by log2(e)/sqrt(128), exp -> exp2
//   vT[h*128+dh][t] = sum_l W_uv[h*128+dh, l] * c_kv[t,l]  (transposed for PV B-frags)
// Attention: causal-paired q-tiles (p,31-p), XCD-grouped grid, K+V dbuf LDS.
// ROUND 9: 2 waves x 32 q-rows (2 rowgroups) per block -- K/V LDS fragment reads
// amortized over 2x q-rows (DS pipe was ~78% occupied at 16 rows/wave).
// launch_bounds(128,1): 1 wave/SIMD, 512-VGPR budget.

typedef __bf16 bf16x8 __attribute__((ext_vector_type(8)));
typedef __bf16 bf16x4 __attribute__((ext_vector_type(4)));
typedef float  f32x4  __attribute__((ext_vector_type(4)));

#define GLOBAL_AS __attribute__((address_space(1)))
#define LDS_AS    __attribute__((address_space(3)))

__device__ __forceinline__ void gload_lds16(const void* g, void* l) {
    __builtin_amdgcn_global_load_lds((const GLOBAL_AS uint32_t*)g,
                                     (LDS_AS uint32_t*)l, 16, 0, 0);
}

// ---------------- fused prep: f32->bf16 casts (5 tensors) + W_uk transpose ----------------
__global__ void k_prep(const float* __restrict__ x, const float* __restrict__ wq,
                       const float* __restrict__ wdkv, const float* __restrict__ wuv,
                       const float* __restrict__ wo, const float* __restrict__ wuk,
                       __bf16* __restrict__ xb, __bf16* __restrict__ wqb,
                       __bf16* __restrict__ wdkvb, __bf16* __restrict__ wuvb,
                       __bf16* __restrict__ wob, __bf16* __restrict__ wukT) {
    __shared__ float t[64][65];
    const int bidx = blockIdx.x;
    if (bidx < 9216) {
        long i = (long)bidx * blockDim.x + threadIdx.x;  // 8-elem group id
        const float* src; __bf16* dst; long off;
        if (i < 1048576)      { src = x;    dst = xb;    off = i; }
        else if (i < 1572864) { src = wq;   dst = wqb;   off = i - 1048576; }
        else if (i < 1703936) { src = wdkv; dst = wdkvb; off = i - 1572864; }
        else if (i < 1835008) { src = wuv;  dst = wuvb;  off = i - 1703936; }
        else                  { src = wo;   dst = wob;   off = i - 1835008; }
        long e = off * 8;
        float4 a = *reinterpret_cast<const float4*>(src + e);
        float4 b = *reinterpret_cast<const float4*>(src + e + 4);
        bf16x8 r;
        r[0] = (__bf16)a.x; r[1] = (__bf16)a.y; r[2] = (__bf16)a.z; r[3] = (__bf16)a.w;
        r[4] = (__bf16)b.x; r[5] = (__bf16)b.y; r[6] = (__bf16)b.z; r[7] = (__bf16)b.w;
        *reinterpret_cast<bf16x8*>(dst + e) = r;
    } else {
        const int tb = bidx - 9216;                 // 256 blocks
        const int d0 = (tb & 31) * 64, l0 = (tb >> 5) * 64;
        const int tid = threadIdx.x;
        const int r = tid >> 4, c = (tid & 15) * 4;
        #pragma unroll
        for (int rr = 0; rr < 64; rr += 16) {
            float4 v = *reinterpret_cast<const float4*>(&wuk[(long)(d0 + r + rr) * 512 + l0 + c]);
            t[r + rr][c] = v.x; t[r + rr][c + 1] = v.y;
            t[r + rr][c + 2] = v.z; t[r + rr][c + 3] = v.w;
        }
        __syncthreads();
        const int lr = tid >> 2, dc = (tid & 3) * 16;
        bf16x8 o0, o1;
        #pragma unroll
        for (int i = 0; i < 8; ++i) { o0[i] = (__bf16)t[dc + i][lr]; o1[i] = (__bf16)t[dc + 8 + i][lr]; }
        *reinterpret_cast<bf16x8*>(&wukT[(long)(l0 + lr) * 2048 + d0 + dc]) = o0;
        *reinterpret_cast<bf16x8*>(&wukT[(long)(l0 + lr) * 2048 + d0 + dc + 8]) = o1;
    }
}

// ---------------- merged G1+G2 ----------------
__global__ __launch_bounds__(256, 2) void k_gemm_g12(
    const __bf16* __restrict__ Wqb, const __bf16* __restrict__ WukT, __bf16* __restrict__ absk,
    const __bf16* __restrict__ xb, const __bf16* __restrict__ Wdkvb, float* __restrict__ ckvpre,
    float cscale)
{
    __shared__ __bf16 Asm[128][64];
    __shared__ __bf16 Bsm[64][64];
    const int bid = blockIdx.x;
    const bool g1s = (bid < 128);
    const int lbid = g1s ? bid : bid - 128;
    const int tm = (lbid >> 3) * 128, tn = (lbid & 7) * 64;
    const __bf16* A = g1s ? Wqb : xb;
    const __bf16* B = g1s ? WukT : Wdkvb;
    const int tid  = threadIdx.x;
    const int lane = tid & 63, wid = tid >> 6;
    const int r16 = lane & 15, g = lane >> 4;
    const int srow  = lane >> 3;
    const int sslot = lane & 7;
    const int scol  = ((sslot ^ srow) * 8);

    f32x4 acc[2][4];
    #pragma unroll
    for (int m = 0; m < 2; ++m)
        #pragma unroll
        for (int n = 0; n < 4; ++n) acc[m][n] = (f32x4){0.f, 0.f, 0.f, 0.f};

    for (int kt = 0; kt < 2048; kt += 64) {
        __syncthreads();
        #pragma unroll
        for (int c2 = 0; c2 < 4; ++c2) {
            const int chunk = wid * 4 + c2;
            const int row   = chunk * 8 + srow;
            gload_lds16(&A[(long)(tm + row) * 2048 + kt + scol], &Asm[chunk * 8][0]);
        }
        #pragma unroll
        for (int c2 = 0; c2 < 2; ++c2) {
            const int chunk = wid * 2 + c2;
            const int row   = chunk * 8 + srow;
            gload_lds16(&B[(long)(tn + row) * 2048 + kt + scol], &Bsm[chunk * 8][0]);
        }
        __syncthreads();
        #pragma unroll
        for (int kk = 0; kk < 2; ++kk) {
            bf16x8 af[2], bfr[4];
            #pragma unroll
            for (int m = 0; m < 2; ++m) {
                const int row = wid * 32 + m * 16 + r16;
                af[m] = *reinterpret_cast<const bf16x8*>(
                    reinterpret_cast<const char*>(&Asm[0][0]) +
                    row * 128 + (((kk * 4 + g) ^ (row & 7)) * 16));
            }
            #pragma unroll
            for (int n = 0; n < 4; ++n) {
                const int row = n * 16 + r16;
                bfr[n] = *reinterpret_cast<const bf16x8*>(
                    reinterpret_cast<const char*>(&Bsm[0][0]) +
                    row * 128 + (((kk * 4 + g) ^ (row & 7)) * 16));
            }
            #pragma unroll
            for (int m = 0; m < 2; ++m)
                #pragma unroll
                for (int n = 0; n < 4; ++n)
                    acc[m][n] = __builtin_amdgcn_mfma_f32_16x16x32_bf16(af[m], bfr[n], acc[m][n], 0, 0, 0);
        }
    }
    #pragma unroll
    for (int m = 0; m < 2; ++m) {
        #pragma unroll
        for (int n = 0; n < 4; ++n) {
            #pragma unroll
            for (int j = 0; j < 4; ++j) {
                const int row = tm + wid * 32 + m * 16 + g * 4 + j;
                const int col = tn + n * 16 + r16;
                if (g1s) absk[(long)row * 512 + col] = (__bf16)(acc[m][n][j] * cscale);
                else     ckvpre[(long)row * 512 + col] = acc[m][n][j];
            }
        }
    }
}

// ---------------- generic bf16 GEMM, C = cmul * (A * B^T) ----------------
template <typename CT>
__global__ __launch_bounds__(256, 2) void k_gemm_bt(
    const __bf16* __restrict__ A, const __bf16* __restrict__ B, CT* __restrict__ C,
    int K, int lda, int ldb, int ldc,
    long aOffZ, long bOffZ, long cOffZ, float cmul)
{
    A += (long)blockIdx.z * aOffZ;
    B += (long)blockIdx.z * bOffZ;
    C += (long)blockIdx.z * cOffZ;
    __shared__ __bf16 Asm[128][64];
    __shared__ __bf16 Bsm[128][64];
    const int tid  = threadIdx.x;
    const int lane = tid & 63, wid = tid >> 6;
    const int wr = wid >> 1, wc = wid & 1;
    const int tm = blockIdx.x * 128, tn = blockIdx.y * 128;
    const int r16 = lane & 15, g = lane >> 4;

    const int srow  = lane >> 3;
    const int sslot = lane & 7;
    const int scol  = ((sslot ^ srow) * 8);

    f32x4 acc[4][4];
    #pragma unroll
    for (int m = 0; m < 4; ++m)
        #pragma unroll
        for (int n = 0; n < 4; ++n) acc[m][n] = (f32x4){0.f, 0.f, 0.f, 0.f};

    for (int kt = 0; kt < K; kt += 64) {
        __syncthreads();
        #pragma unroll
        for (int c2 = 0; c2 < 4; ++c2) {
            const int chunk = wid * 4 + c2;
            const int row   = chunk * 8 + srow;
            gload_lds16(&A[(long)(tm + row) * lda + kt + scol], &Asm[chunk * 8][0]);
            gload_lds16(&B[(long)(tn + row) * ldb + kt + scol], &Bsm[chunk * 8][0]);
        }
        __syncthreads();
        #pragma unroll
        for (int kk = 0; kk < 2; ++kk) {
            bf16x8 af[4], bfr[4];
            #pragma unroll
            for (int m = 0; m < 4; ++m) {
                const int row = wr * 64 + m * 16 + r16;
                af[m] = *reinterpret_cast<const bf16x8*>(
                    reinterpret_cast<const char*>(&Asm[0][0]) +
                    row * 128 + (((kk * 4 + g) ^ (row & 7)) * 16));
            }
            #pragma unroll
            for (int n = 0; n < 4; ++n) {
                const int row = wc * 64 + n * 16 + r16;
                bfr[n] = *reinterpret_cast<const bf16x8*>(
                    reinterpret_cast<const char*>(&Bsm[0][0]) +
                    row * 128 + (((kk * 4 + g) ^ (row & 7)) * 16));
            }
            #pragma unroll
            for (int m = 0; m < 4; ++m)
                #pragma unroll
                for (int n = 0; n < 4; ++n)
                    acc[m][n] = __builtin_amdgcn_mfma_f32_16x16x32_bf16(af[m], bfr[n], acc[m][n], 0, 0, 0);
        }
    }
    #pragma unroll
    for (int m = 0; m < 4; ++m) {
        #pragma unroll
        for (int n = 0; n < 4; ++n) {
            #pragma unroll
            for (int j = 0; j < 4; ++j) {
                const int row = tm + wr * 64 + m * 16 + g * 4 + j;
                const int col = tn + wc * 64 + n * 16 + r16;
                C[(long)row * ldc + col] = (CT)(acc[m][n][j] * cmul);
            }
        }
    }
}

// ---------------- LayerNorm over L=512, one wave per row ----------------
__global__ void k_layernorm(const float* __restrict__ pre, const float* __restrict__ gamma,
                            const float* __restrict__ beta, float* __restrict__ out_f32,
                            __bf16* __restrict__ out_bf16) {
    const int row  = blockIdx.x * 4 + (threadIdx.x >> 6);
    const int lane = threadIdx.x & 63;
    const float* p = pre + (long)row * 512;
    float4 v0 = *reinterpret_cast<const float4*>(p + lane * 4);
    float4 v1 = *reinterpret_cast<const float4*>(p + 256 + lane * 4);
    float s  = v0.x + v0.y + v0.z + v0.w + v1.x + v1.y + v1.z + v1.w;
    float s2 = v0.x*v0.x + v0.y*v0.y + v0.z*v0.z + v0.w*v0.w
             + v1.x*v1.x + v1.y*v1.y + v1.z*v1.z + v1.w*v1.w;
    #pragma unroll
    for (int d = 1; d < 64; d <<= 1) { s += __shfl_xor(s, d); s2 += __shfl_xor(s2, d); }
    const float mu  = s * (1.0f / 512.0f);
    const float var = s2 * (1.0f / 512.0f) - mu * mu;
    const float rs  = rsqrtf(var + 1e-5f);
    float4 g0 = *reinterpret_cast<const float4*>(gamma + lane * 4);
    float4 g1 = *reinterpret_cast<const float4*>(gamma + 256 + lane * 4);
    float4 b0 = *reinterpret_cast<const float4*>(beta + lane * 4);
    float4 b1 = *reinterpret_cast<const float4*>(beta + 256 + lane * 4);
    float4 y0, y1;
    y0.x = (v0.x - mu) * rs * g0.x + b0.x;  y0.y = (v0.y - mu) * rs * g0.y + b0.y;
    y0.z = (v0.z - mu) * rs * g0.z + b0.z;  y0.w = (v0.w - mu) * rs * g0.w + b0.w;
    y1.x = (v1.x - mu) * rs * g1.x + b1.x;  y1.y = (v1.y - mu) * rs * g1.y + b1.y;
    y1.z = (v1.z - mu) * rs * g1.z + b1.z;  y1.w = (v1.w - mu) * rs * g1.w + b1.w;
    *reinterpret_cast<float4*>(out_f32 + (long)row * 512 + lane * 4) = y0;
    *reinterpret_cast<float4*>(out_f32 + (long)row * 512 + 256 + lane * 4) = y1;
    bf16x4 z0, z1;
    z0[0] = (__bf16)y0.x; z0[1] = (__bf16)y0.y; z0[2] = (__bf16)y0.z; z0[3] = (__bf16)y0.w;
    z1[0] = (__bf16)y1.x; z1[1] = (__bf16)y1.y; z1[2] = (__bf16)y1.z; z1[3] = (__bf16)y1.w;
    *reinterpret_cast<bf16x4*>(out_bf16 + (long)row * 512 + lane * 4) = z0;
    *reinterpret_cast<bf16x4*>(out_bf16 + (long)row * 512 + 256 + lane * 4) = z1;
}

// ---------------- causal flash attention: 2 waves x 32 q-rows ----------------
// 1-D grid of 512 blocks, XCD-grouped. Block p owns q-tiles {p, 31-p}; wave wid
// owns rows wid*32..wid*32+31 (rowgroups rg=0,1 of 16). K/V staged into dbuf LDS
// by both waves; each K/V fragment read feeds 2 rowgroups x 2 streams (4 MFMAs).
// launch_bounds(128,1): 1 wave/SIMD, 512-VGPR budget, 2 blocks/CU (LDS-limited).
__global__ __launch_bounds__(128, 1) void k_attn(
    const __bf16* __restrict__ xb,
    const __bf16* __restrict__ Keff,
    const __bf16* __restrict__ vT,
    __bf16* __restrict__ ctx)
{
    __shared__ __bf16 Ks[2][64][128];  // 32 KB
    __shared__ __bf16 Vs[2][128][64];  // 32 KB
    __shared__ __bf16 Pl[2][32][72];   // 9.2 KB, row stride 144B
    const int lane = threadIdx.x & 63;
    const int wid  = threadIdx.x >> 6;        // 0..1
    const int r16  = lane & 15;
    const int g    = lane >> 4;
    const int bid  = blockIdx.x;
    const int gidx = ((bid >> 7) << 3) | (bid & 7);
    const int h = gidx & 15, b = gidx >> 4;
    const int p = (bid >> 3) & 15;
    const int nkt = 32 - p;
    const int qbase[2] = { p * 64 + wid * 32, (31 - p) * 64 + wid * 32 };

    // Q fragments: [stream][rowgroup][ks]
    bf16x8 aQ[2][2][4];
    #pragma unroll
    for (int st = 0; st < 2; ++st)
        #pragma unroll
        for (int rg = 0; rg < 2; ++rg) {
            const __bf16* qp = xb + ((long)(b * 2048 + qbase[st] + rg * 16 + r16)) * 2048 + h * 128 + g * 8;
            #pragma unroll
            for (int ks = 0; ks < 4; ++ks)
                aQ[st][rg][ks] = *reinterpret_cast<const bf16x8*>(qp + ks * 32);
        }

    f32x4 o[2][2][8];
    float mrow[2][2], lrow[2][2];
    #pragma unroll
    for (int st = 0; st < 2; ++st)
        #pragma unroll
        for (int rg = 0; rg < 2; ++rg) {
            #pragma unroll
            for (int d8 = 0; d8 < 8; ++d8) o[st][rg][d8] = (f32x4){0.f, 0.f, 0.f, 0.f};
            mrow[st][rg] = -__builtin_inff(); lrow[st][rg] = 0.f;
        }

    const __bf16* Kb = Keff + (long)h * (4096 * 128) + (long)b * (2048 * 128);
    const __bf16* Vb = vT + (long)h * (128 * 4096) + b * 2048;

    // staging geometry, 128 threads: K row=c*8+wid*4+(lane>>4), V row=c*16+wid*8+(lane>>3)
    const int ksrow = wid * 4 + (lane >> 4);
    const int kslot = lane & 15;
    const int vsrow = wid * 8 + (lane >> 3);
    const int vslot = lane & 7;

    auto stage = [&](int kt, int buf) {
        const int k0s = kt * 64;
        #pragma unroll
        for (int c = 0; c < 8; ++c) {
            const int row = c * 8 + ksrow;
            const int gcol = ((kslot ^ (row & 15)) << 3);
            gload_lds16(&Kb[(long)(k0s + row) * 128 + gcol], &Ks[buf][c * 8 + wid * 4][0]);
        }
        #pragma unroll
        for (int c = 0; c < 8; ++c) {
            const int row = c * 16 + vsrow;
            const int gcol = ((vslot ^ (row & 7)) << 3);
            gload_lds16(&Vb[(long)row * 4096 + k0s + gcol], &Vs[buf][c * 16 + wid * 8][0]);
        }
    };

    const float THR = 11.541560327f;   // 8 * log2(e)
    stage(0, 0);
    for (int kt = 0; kt < nkt; ++kt) {
        const int cur = kt & 1;
        const int k0 = kt * 64;
        __syncthreads();                         // drains vmcnt: buf[cur] ready
        if (kt + 1 < nkt) stage(kt + 1, cur ^ 1);  // prefetch overlaps compute below
        const char* Kbase = reinterpret_cast<const char*>(&Ks[cur][0][0]);
        const char* Vbase = reinterpret_cast<const char*>(&Vs[cur][0][0]);
        const bool light = (kt <= p);

        // QK^T swapped; each K-frag feeds 2 rowgroups x (1 or 2) streams
        f32x4 sT[2][2][4];                        // [st][rg][kh]
        #pragma unroll
        for (int st = 0; st < 2; ++st)
            #pragma unroll
            for (int rg = 0; rg < 2; ++rg)
                #pragma unroll
                for (int kh = 0; kh < 4; ++kh) sT[st][rg][kh] = (f32x4){0.f, 0.f, 0.f, 0.f};
        __builtin_amdgcn_s_setprio(1);
        #pragma unroll
        for (int kh = 0; kh < 4; ++kh) {
            const int krow = kh * 16 + r16;
            bf16x8 bk[4];
            #pragma unroll
            for (int ks = 0; ks < 4; ++ks)
                bk[ks] = *reinterpret_cast<const bf16x8*>(
                    Kbase + krow * 256 + (((ks * 4 + g) ^ (krow & 15)) * 16));
            #pragma unroll
            for (int ks = 0; ks < 4; ++ks) {
                sT[1][0][kh] = __builtin_amdgcn_mfma_f32_16x16x32_bf16(bk[ks], aQ[1][0][ks], sT[1][0][kh], 0, 0, 0);
                sT[1][1][kh] = __builtin_amdgcn_mfma_f32_16x16x32_bf16(bk[ks], aQ[1][1][ks], sT[1][1][kh], 0, 0, 0);
            }
            if (light) {
                #pragma unroll
                for (int ks = 0; ks < 4; ++ks) {
                    sT[0][0][kh] = __builtin_amdgcn_mfma_f32_16x16x32_bf16(bk[ks], aQ[0][0][ks], sT[0][0][kh], 0, 0, 0);
                    sT[0][1][kh] = __builtin_amdgcn_mfma_f32_16x16x32_bf16(bk[ks], aQ[0][1][ks], sT[0][1][kh], 0, 0, 0);
                }
            }
        }
        __builtin_amdgcn_s_setprio(0);

        // per-(stream,rowgroup) softmax -> Pl roundtrip -> pa frags
        bf16x8 pa[2][2][2];                      // [st][rg][kk]
        #pragma unroll
        for (int sti = 0; sti < 2; ++sti) {
            const int st = 1 - sti;              // stream 1 first
            if (st == 0 && !light) continue;
            const bool diag = (st == 0) ? (kt == p) : (kt == nkt - 1);
            #pragma unroll
            for (int rg = 0; rg < 2; ++rg) {
                if (diag) {
                    const int qabs = qbase[st] + rg * 16 + r16;
                    #pragma unroll
                    for (int kh = 0; kh < 4; ++kh)
                        #pragma unroll
                        for (int j = 0; j < 4; ++j)
                            if (k0 + kh * 16 + g * 4 + j > qabs) sT[st][rg][kh][j] = -1e30f;
                }
                float t01 = fmaxf(sT[st][rg][0][0], sT[st][rg][0][1]), t23 = fmaxf(sT[st][rg][0][2], sT[st][rg][0][3]);
                float t45 = fmaxf(sT[st][rg][1][0], sT[st][rg][1][1]), t67 = fmaxf(sT[st][rg][1][2], sT[st][rg][1][3]);
                float t89 = fmaxf(sT[st][rg][2][0], sT[st][rg][2][1]), tab = fmaxf(sT[st][rg][2][2], sT[st][rg][2][3]);
                float tcd = fmaxf(sT[st][rg][3][0], sT[st][rg][3][1]), tef = fmaxf(sT[st][rg][3][2], sT[st][rg][3][3]);
                float tmax = fmaxf(fmaxf(fmaxf(t01, t23), fmaxf(t45, t67)),
                                   fmaxf(fmaxf(t89, tab), fmaxf(tcd, tef)));
                tmax = fmaxf(tmax, __shfl_xor(tmax, 16));
                tmax = fmaxf(tmax, __shfl_xor(tmax, 32));
                const int needi = !__all(tmax <= mrow[st][rg] + THR);
                float m = mrow[st][rg], alpha = 1.f;
                if (needi) {
                    const float mnew = fmaxf(m, tmax);
                    alpha = __builtin_amdgcn_exp2f(m - mnew);   // exp2(-inf)=0 first tile
                    m = mnew; mrow[st][rg] = mnew;
                }
                float rsum = 0.f;
                bf16x4 pb[4];
                #pragma unroll
                for (int kh = 0; kh < 4; ++kh) {
                    #pragma unroll
                    for (int j = 0; j < 4; ++j) {
                        const float pv = __builtin_amdgcn_exp2f(sT[st][rg][kh][j] - m);
                        rsum += pv;
                        pb[kh][j] = (__bf16)pv;
                    }
                }
                rsum += __shfl_xor(rsum, 16);
                rsum += __shfl_xor(rsum, 32);
                lrow[st][rg] = lrow[st][rg] * alpha + rsum;
                #pragma unroll
                for (int kh = 0; kh < 4; ++kh)
                    *reinterpret_cast<bf16x4*>(&Pl[wid][rg * 16 + r16][kh * 16 + g * 4]) = pb[kh];
                pa[st][rg][0] = *reinterpret_cast<const bf16x8*>(&Pl[wid][rg * 16 + r16][g * 8]);
                pa[st][rg][1] = *reinterpret_cast<const bf16x8*>(&Pl[wid][rg * 16 + r16][32 + g * 8]);
                if (needi) {
                    float a4[4];
                    #pragma unroll
                    for (int j = 0; j < 4; ++j) a4[j] = __shfl(alpha, g * 4 + j);
                    #pragma unroll
                    for (int d8 = 0; d8 < 8; ++d8) {
                        o[st][rg][d8][0] *= a4[0]; o[st][rg][d8][1] *= a4[1];
                        o[st][rg][d8][2] *= a4[2]; o[st][rg][d8][3] *= a4[3];
                    }
                }
            }
        }

        // PV: each V-frag feeds 2 rowgroups x (1 or 2) streams
        __builtin_amdgcn_s_setprio(1);
        #pragma unroll
        for (int kk = 0; kk < 2; ++kk) {
            #pragma unroll
            for (int d8 = 0; d8 < 8; ++d8) {
                const int vrow = d8 * 16 + r16;
                bf16x8 bv = *reinterpret_cast<const bf16x8*>(
                    Vbase + vrow * 128 + (((kk * 4 + g) ^ (vrow & 7)) * 16));
                o[1][0][d8] = __builtin_amdgcn_mfma_f32_16x16x32_bf16(pa[1][0][kk], bv, o[1][0][d8], 0, 0, 0);
                o[1][1][d8] = __builtin_amdgcn_mfma_f32_16x16x32_bf16(pa[1][1][kk], bv, o[1][1][d8], 0, 0, 0);
                if (light) {
                    o[0][0][d8] = __builtin_amdgcn_mfma_f32_16x16x32_bf16(pa[0][0][kk], bv, o[0][0][d8], 0, 0, 0);
                    o[0][1][d8] = __builtin_amdgcn_mfma_f32_16x16x32_bf16(pa[0][1][kk], bv, o[0][1][d8], 0, 0, 0);
                }
            }
        }
        __builtin_amdgcn_s_setprio(0);
    }
    #pragma unroll
    for (int st = 0; st < 2; ++st) {
        #pragma unroll
        for (int rg = 0; rg < 2; ++rg) {
            float rl4[4];
            #pragma unroll
            for (int j = 0; j < 4; ++j) rl4[j] = 1.0f / __shfl(lrow[st][rg], g * 4 + j);
            #pragma unroll
            for (int d8 = 0; d8 < 8; ++d8) {
                #pragma unroll
                for (int j = 0; j < 4; ++j) {
                    const int row = qbase[st] + rg * 16 + g * 4 + j;
                    ctx[((long)(b * 2048 + row)) * 2048 + h * 128 + d8 * 16 + r16] =
                        (__bf16)(o[st][rg][d8][j] * rl4[j]);
                }
            }
        }
    }
}

extern "C" void kernel_launch(void* const* d_in, const int* in_sizes, int n_in,
                              void* d_out, int out_size, void* d_ws, size_t ws_size,
                              hipStream_t stream) {
    const float* x     = (const float*)d_in[0];
    const float* W_q   = (const float*)d_in[1];
    const float* Wd_kv = (const float*)d_in[2];
    const float* W_uv  = (const float*)d_in[3];
    const float* W_uk  = (const float*)d_in[4];
    const float* W_o   = (const float*)d_in[5];
    const float* gamma = (const float*)d_in[6];
    const float* beta  = (const float*)d_in[7];
    float* out     = (float*)d_out;             // [2,2048,2048]
    float* ckv_out = out + 8388608;             // [2,2048,512]

    // workspace layout (bytes), total 100 MB
    char* ws = (char*)d_ws;
    __bf16* xb     = (__bf16*)(ws + 0);           // 16 MB  x bf16 [4096][2048]
    __bf16* Wqb    = (__bf16*)(ws + 16777216);    //  8 MB
    __bf16* Wdkvb  = (__bf16*)(ws + 25165824);    //  2 MB
    __bf16* Wuvb   = (__bf16*)(ws + 27262976);    //  2 MB
    __bf16* Wob    = (__bf16*)(ws + 29360128);    //  8 MB
    __bf16* WukT   = (__bf16*)(ws + 37748736);    //  2 MB  [512][2048]
    __bf16* absk   = (__bf16*)(ws + 39845888);    //  2 MB  absorbed_k [2048][512] (pre-scaled)
    float*  ckvpre = (float*) (ws + 41943040);    //  8 MB  pre-LN [4096][512] f32
    __bf16* ckvb   = (__bf16*)(ws + 50331648);    //  4 MB  c_kv bf16 [4096][512]
    __bf16* Keff   = (__bf16*)(ws + 54525952);    // 16 MB  [16][4096][128]
    __bf16* vT     = (__bf16*)(ws + 71303168);    // 16 MB  [2048][4096]
    __bf16* ctx    = (__bf16*)(ws + 88080384);    // 16 MB  [4096][2048]

    // fused casts + transpose (one launch)
    k_prep<<<9472, 256, 0, stream>>>(x, W_q, Wd_kv, W_uv, W_o, W_uk,
                                     xb, Wqb, Wdkvb, Wuvb, Wob, WukT);

    // scores scale folded into absorbed_k: log2(e)/sqrt(128)
    const float cscale = 1.4426950408889634f * 0.08838834764831845f;
    // merged G1 (absk, bf16, scaled) + G2 (ckvpre, f32): 384 blocks
    k_gemm_g12<<<384, 256, 0, stream>>>(Wqb, WukT, absk, xb, Wdkvb, ckvpre, cscale);
    // LN -> c_kv f32 (output 1) + bf16
    k_layernorm<<<1024, 256, 0, stream>>>(ckvpre, gamma, beta, ckv_out, ckvb);
    // G3: K_eff[h][4096][128] = c_kv * absorbed_k[h]^T  (grid.z = heads)
    k_gemm_bt<__bf16><<<dim3(32, 1, 16), 256, 0, stream>>>(ckvb, absk, Keff,
        512, 512, 512, 128, 0, 128 * 512, 4096 * 128, 1.0f);
    // G4: vT[2048][4096] = W_uv * c_kv^T   (v_full transposed)
    k_gemm_bt<__bf16><<<dim3(16, 32, 1), 256, 0, stream>>>(Wuvb, ckvb, vT,
        512, 512, 512, 4096, 0, 0, 0, 1.0f);
    // attention -> ctx bf16 [4096][2048]  (XCD-grouped 1-D grid, 128 threads)
    k_attn<<<512, 128, 0, stream>>>(xb, Keff, vT, ctx);
    // G5: out[4096][2048] = ctx * W_o^T  (f32 to d_out)
    k_gemm_bt<float><<<dim3(32, 16, 1), 256, 0, stream>>>(ctx, Wob, out,
        2048, 2048, 2048, 2048, 0, 0, 0, 1.0f);
}

// Round 10
// 201.441 us; speedup vs baseline: 1.1991x; 1.1991x over previous
//
#include <hip/hip_runtime.h>
#include <hip/hip_bf16.h>
#include <cstdint>

// RopelessMLA forward, MI355X/gfx950.
// B=2, S=2048, D=2048, H=16, DH=128, L=512. Outputs: out [2,2048,2048] f32, c_kv [2,2048,512] f32.
//
// Restructuring:
//   K_eff[h,t,dh] = sum_l c_kv[t,l] * absorbed_k[h,dh,l]   (absorb into keys, QK^T K-dim = 128)
//   scores (log2-domain): absorbed_k pre-scaled by log2(e)/sqrt(128), exp -> exp2
//   vT[h*128+dh][t] = sum_l W_uv[h*128+dh, l] * c_kv[t,l]  (transposed for PV B-frags)
// Attention = round-8 config (measured 77us; best of R5-R9 A/Bs):
//   4 waves x (16+16) q-rows, causal-paired q-tiles (p,31-p), XCD-grouped grid,
//   K+V dbuf LDS shared across streams, swapped QK^T, log2 softmax, defer-max,
//   diag-only mask, setprio, launch_bounds(256,2).
//   REFUTED: V-direct-global (R7: 145us), 2-wave/32-row blocks (R9: 127us, 1 wave/SIMD),
//   launch_bounds(256,3) (R6: spill).

typedef __bf16 bf16x8 __attribute__((ext_vector_type(8)));
typedef __bf16 bf16x4 __attribute__((ext_vector_type(4)));
typedef float  f32x4  __attribute__((ext_vector_type(4)));

#define GLOBAL_AS __attribute__((address_space(1)))
#define LDS_AS    __attribute__((address_space(3)))

__device__ __forceinline__ void gload_lds16(const void* g, void* l) {
    __builtin_amdgcn_global_load_lds((const GLOBAL_AS uint32_t*)g,
                                     (LDS_AS uint32_t*)l, 16, 0, 0);
}

// ---------------- fused prep: f32->bf16 casts (5 tensors) + W_uk transpose ----------------
__global__ void k_prep(const float* __restrict__ x, const float* __restrict__ wq,
                       const float* __restrict__ wdkv, const float* __restrict__ wuv,
                       const float* __restrict__ wo, const float* __restrict__ wuk,
                       __bf16* __restrict__ xb, __bf16* __restrict__ wqb,
                       __bf16* __restrict__ wdkvb, __bf16* __restrict__ wuvb,
                       __bf16* __restrict__ wob, __bf16* __restrict__ wukT) {
    __shared__ float t[64][65];
    const int bidx = blockIdx.x;
    if (bidx < 9216) {
        long i = (long)bidx * blockDim.x + threadIdx.x;  // 8-elem group id
        const float* src; __bf16* dst; long off;
        if (i < 1048576)      { src = x;    dst = xb;    off = i; }
        else if (i < 1572864) { src = wq;   dst = wqb;   off = i - 1048576; }
        else if (i < 1703936) { src = wdkv; dst = wdkvb; off = i - 1572864; }
        else if (i < 1835008) { src = wuv;  dst = wuvb;  off = i - 1703936; }
        else                  { src = wo;   dst = wob;   off = i - 1835008; }
        long e = off * 8;
        float4 a = *reinterpret_cast<const float4*>(src + e);
        float4 b = *reinterpret_cast<const float4*>(src + e + 4);
        bf16x8 r;
        r[0] = (__bf16)a.x; r[1] = (__bf16)a.y; r[2] = (__bf16)a.z; r[3] = (__bf16)a.w;
        r[4] = (__bf16)b.x; r[5] = (__bf16)b.y; r[6] = (__bf16)b.z; r[7] = (__bf16)b.w;
        *reinterpret_cast<bf16x8*>(dst + e) = r;
    } else {
        const int tb = bidx - 9216;                 // 256 blocks
        const int d0 = (tb & 31) * 64, l0 = (tb >> 5) * 64;
        const int tid = threadIdx.x;
        const int r = tid >> 4, c = (tid & 15) * 4;
        #pragma unroll
        for (int rr = 0; rr < 64; rr += 16) {
            float4 v = *reinterpret_cast<const float4*>(&wuk[(long)(d0 + r + rr) * 512 + l0 + c]);
            t[r + rr][c] = v.x; t[r + rr][c + 1] = v.y;
            t[r + rr][c + 2] = v.z; t[r + rr][c + 3] = v.w;
        }
        __syncthreads();
        const int lr = tid >> 2, dc = (tid & 3) * 16;
        bf16x8 o0, o1;
        #pragma unroll
        for (int i = 0; i < 8; ++i) { o0[i] = (__bf16)t[dc + i][lr]; o1[i] = (__bf16)t[dc + 8 + i][lr]; }
        *reinterpret_cast<bf16x8*>(&wukT[(long)(l0 + lr) * 2048 + d0 + dc]) = o0;
        *reinterpret_cast<bf16x8*>(&wukT[(long)(l0 + lr) * 2048 + d0 + dc + 8]) = o1;
    }
}

// ---------------- merged G1+G2 ----------------
__global__ __launch_bounds__(256, 2) void k_gemm_g12(
    const __bf16* __restrict__ Wqb, const __bf16* __restrict__ WukT, __bf16* __restrict__ absk,
    const __bf16* __restrict__ xb, const __bf16* __restrict__ Wdkvb, float* __restrict__ ckvpre,
    float cscale)
{
    __shared__ __bf16 Asm[128][64];
    __shared__ __bf16 Bsm[64][64];
    const int bid = blockIdx.x;
    const bool g1s = (bid < 128);
    const int lbid = g1s ? bid : bid - 128;
    const int tm = (lbid >> 3) * 128, tn = (lbid & 7) * 64;
    const __bf16* A = g1s ? Wqb : xb;
    const __bf16* B = g1s ? WukT : Wdkvb;
    const int tid  = threadIdx.x;
    const int lane = tid & 63, wid = tid >> 6;
    const int r16 = lane & 15, g = lane >> 4;
    const int srow  = lane >> 3;
    const int sslot = lane & 7;
    const int scol  = ((sslot ^ srow) * 8);

    f32x4 acc[2][4];
    #pragma unroll
    for (int m = 0; m < 2; ++m)
        #pragma unroll
        for (int n = 0; n < 4; ++n) acc[m][n] = (f32x4){0.f, 0.f, 0.f, 0.f};

    for (int kt = 0; kt < 2048; kt += 64) {
        __syncthreads();
        #pragma unroll
        for (int c2 = 0; c2 < 4; ++c2) {
            const int chunk = wid * 4 + c2;
            const int row   = chunk * 8 + srow;
            gload_lds16(&A[(long)(tm + row) * 2048 + kt + scol], &Asm[chunk * 8][0]);
        }
        #pragma unroll
        for (int c2 = 0; c2 < 2; ++c2) {
            const int chunk = wid * 2 + c2;
            const int row   = chunk * 8 + srow;
            gload_lds16(&B[(long)(tn + row) * 2048 + kt + scol], &Bsm[chunk * 8][0]);
        }
        __syncthreads();
        #pragma unroll
        for (int kk = 0; kk < 2; ++kk) {
            bf16x8 af[2], bfr[4];
            #pragma unroll
            for (int m = 0; m < 2; ++m) {
                const int row = wid * 32 + m * 16 + r16;
                af[m] = *reinterpret_cast<const bf16x8*>(
                    reinterpret_cast<const char*>(&Asm[0][0]) +
                    row * 128 + (((kk * 4 + g) ^ (row & 7)) * 16));
            }
            #pragma unroll
            for (int n = 0; n < 4; ++n) {
                const int row = n * 16 + r16;
                bfr[n] = *reinterpret_cast<const bf16x8*>(
                    reinterpret_cast<const char*>(&Bsm[0][0]) +
                    row * 128 + (((kk * 4 + g) ^ (row & 7)) * 16));
            }
            #pragma unroll
            for (int m = 0; m < 2; ++m)
                #pragma unroll
                for (int n = 0; n < 4; ++n)
                    acc[m][n] = __builtin_amdgcn_mfma_f32_16x16x32_bf16(af[m], bfr[n], acc[m][n], 0, 0, 0);
        }
    }
    #pragma unroll
    for (int m = 0; m < 2; ++m) {
        #pragma unroll
        for (int n = 0; n < 4; ++n) {
            #pragma unroll
            for (int j = 0; j < 4; ++j) {
                const int row = tm + wid * 32 + m * 16 + g * 4 + j;
                const int col = tn + n * 16 + r16;
                if (g1s) absk[(long)row * 512 + col] = (__bf16)(acc[m][n][j] * cscale);
                else     ckvpre[(long)row * 512 + col] = acc[m][n][j];
            }
        }
    }
}

// ---------------- merged G3+G4 (both bf16 K=512 GEMMs off ckvb) ----------------
// blocks [0,512): G3  Keff[h][4096][128] = ckvb * absk[h]^T   (32 m-tiles x 16 heads)
// blocks [512,1024): G4  vT[2048][4096] = Wuvb * ckvb^T       (16 x 32 tiles)
// Identical validated 128^2 body; block-uniform operand decode.
__global__ __launch_bounds__(256, 2) void k_gemm_g34(
    const __bf16* __restrict__ ckvb, const __bf16* __restrict__ absk,
    __bf16* __restrict__ Keff, const __bf16* __restrict__ Wuvb, __bf16* __restrict__ vT)
{
    __shared__ __bf16 Asm[128][64];
    __shared__ __bf16 Bsm[128][64];
    const int bid = blockIdx.x;
    const bool g3s = (bid < 512);
    const __bf16* A;
    const __bf16* B;
    __bf16* C;
    int tm, tn, ldc;
    if (g3s) {
        const int m = bid >> 4, h = bid & 15;     // 32 m-tiles x 16 heads
        A = ckvb; B = absk + (long)h * (128 * 512);
        C = Keff + (long)h * (4096 * 128);
        tm = m * 128; tn = 0; ldc = 128;
    } else {
        const int lb = bid - 512;                 // 16 x 32
        A = Wuvb; B = ckvb;
        C = vT;
        tm = (lb >> 5) * 128; tn = (lb & 31) * 128; ldc = 4096;
    }
    const int tid  = threadIdx.x;
    const int lane = tid & 63, wid = tid >> 6;
    const int wr = wid >> 1, wc = wid & 1;
    const int r16 = lane & 15, g = lane >> 4;
    const int srow  = lane >> 3;
    const int sslot = lane & 7;
    const int scol  = ((sslot ^ srow) * 8);

    f32x4 acc[4][4];
    #pragma unroll
    for (int m = 0; m < 4; ++m)
        #pragma unroll
        for (int n = 0; n < 4; ++n) acc[m][n] = (f32x4){0.f, 0.f, 0.f, 0.f};

    for (int kt = 0; kt < 512; kt += 64) {
        __syncthreads();
        #pragma unroll
        for (int c2 = 0; c2 < 4; ++c2) {
            const int chunk = wid * 4 + c2;
            const int row   = chunk * 8 + srow;
            gload_lds16(&A[(long)(tm + row) * 512 + kt + scol], &Asm[chunk * 8][0]);
            gload_lds16(&B[(long)(tn + row) * 512 + kt + scol], &Bsm[chunk * 8][0]);
        }
        __syncthreads();
        #pragma unroll
        for (int kk = 0; kk < 2; ++kk) {
            bf16x8 af[4], bfr[4];
            #pragma unroll
            for (int m = 0; m < 4; ++m) {
                const int row = wr * 64 + m * 16 + r16;
                af[m] = *reinterpret_cast<const bf16x8*>(
                    reinterpret_cast<const char*>(&Asm[0][0]) +
                    row * 128 + (((kk * 4 + g) ^ (row & 7)) * 16));
            }
            #pragma unroll
            for (int n = 0; n < 4; ++n) {
                const int row = wc * 64 + n * 16 + r16;
                bfr[n] = *reinterpret_cast<const bf16x8*>(
                    reinterpret_cast<const char*>(&Bsm[0][0]) +
                    row * 128 + (((kk * 4 + g) ^ (row & 7)) * 16));
            }
            #pragma unroll
            for (int m = 0; m < 4; ++m)
                #pragma unroll
                for (int n = 0; n < 4; ++n)
                    acc[m][n] = __builtin_amdgcn_mfma_f32_16x16x32_bf16(af[m], bfr[n], acc[m][n], 0, 0, 0);
        }
    }
    #pragma unroll
    for (int m = 0; m < 4; ++m) {
        #pragma unroll
        for (int n = 0; n < 4; ++n) {
            #pragma unroll
            for (int j = 0; j < 4; ++j) {
                const int row = tm + wr * 64 + m * 16 + g * 4 + j;
                const int col = tn + wc * 64 + n * 16 + r16;
                C[(long)row * ldc + col] = (__bf16)acc[m][n][j];
            }
        }
    }
}

// ---------------- generic bf16 GEMM (G5), C = A * B^T, f32 out ----------------
__global__ __launch_bounds__(256, 2) void k_gemm_g5(
    const __bf16* __restrict__ A, const __bf16* __restrict__ B, float* __restrict__ C)
{
    __shared__ __bf16 Asm[128][64];
    __shared__ __bf16 Bsm[128][64];
    const int tid  = threadIdx.x;
    const int lane = tid & 63, wid = tid >> 6;
    const int wr = wid >> 1, wc = wid & 1;
    const int tm = blockIdx.x * 128, tn = blockIdx.y * 128;
    const int r16 = lane & 15, g = lane >> 4;
    const int srow  = lane >> 3;
    const int sslot = lane & 7;
    const int scol  = ((sslot ^ srow) * 8);

    f32x4 acc[4][4];
    #pragma unroll
    for (int m = 0; m < 4; ++m)
        #pragma unroll
        for (int n = 0; n < 4; ++n) acc[m][n] = (f32x4){0.f, 0.f, 0.f, 0.f};

    for (int kt = 0; kt < 2048; kt += 64) {
        __syncthreads();
        #pragma unroll
        for (int c2 = 0; c2 < 4; ++c2) {
            const int chunk = wid * 4 + c2;
            const int row   = chunk * 8 + srow;
            gload_lds16(&A[(long)(tm + row) * 2048 + kt + scol], &Asm[chunk * 8][0]);
            gload_lds16(&B[(long)(tn + row) * 2048 + kt + scol], &Bsm[chunk * 8][0]);
        }
        __syncthreads();
        #pragma unroll
        for (int kk = 0; kk < 2; ++kk) {
            bf16x8 af[4], bfr[4];
            #pragma unroll
            for (int m = 0; m < 4; ++m) {
                const int row = wr * 64 + m * 16 + r16;
                af[m] = *reinterpret_cast<const bf16x8*>(
                    reinterpret_cast<const char*>(&Asm[0][0]) +
                    row * 128 + (((kk * 4 + g) ^ (row & 7)) * 16));
            }
            #pragma unroll
            for (int n = 0; n < 4; ++n) {
                const int row = wc * 64 + n * 16 + r16;
                bfr[n] = *reinterpret_cast<const bf16x8*>(
                    reinterpret_cast<const char*>(&Bsm[0][0]) +
                    row * 128 + (((kk * 4 + g) ^ (row & 7)) * 16));
            }
            #pragma unroll
            for (int m = 0; m < 4; ++m)
                #pragma unroll
                for (int n = 0; n < 4; ++n)
                    acc[m][n] = __builtin_amdgcn_mfma_f32_16x16x32_bf16(af[m], bfr[n], acc[m][n], 0, 0, 0);
        }
    }
    #pragma unroll
    for (int m = 0; m < 4; ++m) {
        #pragma unroll
        for (int n = 0; n < 4; ++n) {
            #pragma unroll
            for (int j = 0; j < 4; ++j) {
                const int row = tm + wr * 64 + m * 16 + g * 4 + j;
                const int col = tn + wc * 64 + n * 16 + r16;
                C[(long)row * 2048 + col] = acc[m][n][j];
            }
        }
    }
}

// ---------------- LayerNorm over L=512, one wave per row ----------------
__global__ void k_layernorm(const float* __restrict__ pre, const float* __restrict__ gamma,
                            const float* __restrict__ beta, float* __restrict__ out_f32,
                            __bf16* __restrict__ out_bf16) {
    const int row  = blockIdx.x * 4 + (threadIdx.x >> 6);
    const int lane = threadIdx.x & 63;
    const float* p = pre + (long)row * 512;
    float4 v0 = *reinterpret_cast<const float4*>(p + lane * 4);
    float4 v1 = *reinterpret_cast<const float4*>(p + 256 + lane * 4);
    float s  = v0.x + v0.y + v0.z + v0.w + v1.x + v1.y + v1.z + v1.w;
    float s2 = v0.x*v0.x + v0.y*v0.y + v0.z*v0.z + v0.w*v0.w
             + v1.x*v1.x + v1.y*v1.y + v1.z*v1.z + v1.w*v1.w;
    #pragma unroll
    for (int d = 1; d < 64; d <<= 1) { s += __shfl_xor(s, d); s2 += __shfl_xor(s2, d); }
    const float mu  = s * (1.0f / 512.0f);
    const float var = s2 * (1.0f / 512.0f) - mu * mu;
    const float rs  = rsqrtf(var + 1e-5f);
    float4 g0 = *reinterpret_cast<const float4*>(gamma + lane * 4);
    float4 g1 = *reinterpret_cast<const float4*>(gamma + 256 + lane * 4);
    float4 b0 = *reinterpret_cast<const float4*>(beta + lane * 4);
    float4 b1 = *reinterpret_cast<const float4*>(beta + 256 + lane * 4);
    float4 y0, y1;
    y0.x = (v0.x - mu) * rs * g0.x + b0.x;  y0.y = (v0.y - mu) * rs * g0.y + b0.y;
    y0.z = (v0.z - mu) * rs * g0.z + b0.z;  y0.w = (v0.w - mu) * rs * g0.w + b0.w;
    y1.x = (v1.x - mu) * rs * g1.x + b1.x;  y1.y = (v1.y - mu) * rs * g1.y + b1.y;
    y1.z = (v1.z - mu) * rs * g1.z + b1.z;  y1.w = (v1.w - mu) * rs * g1.w + b1.w;
    *reinterpret_cast<float4*>(out_f32 + (long)row * 512 + lane * 4) = y0;
    *reinterpret_cast<float4*>(out_f32 + (long)row * 512 + 256 + lane * 4) = y1;
    bf16x4 z0, z1;
    z0[0] = (__bf16)y0.x; z0[1] = (__bf16)y0.y; z0[2] = (__bf16)y0.z; z0[3] = (__bf16)y0.w;
    z1[0] = (__bf16)y1.x; z1[1] = (__bf16)y1.y; z1[2] = (__bf16)y1.z; z1[3] = (__bf16)y1.w;
    *reinterpret_cast<bf16x4*>(out_bf16 + (long)row * 512 + lane * 4) = z0;
    *reinterpret_cast<bf16x4*>(out_bf16 + (long)row * 512 + 256 + lane * 4) = z1;
}

// ---------------- causal flash attention (round-8 config, measured 77us) ----------------
__global__ __launch_bounds__(256, 2) void k_attn(
    const __bf16* __restrict__ xb,
    const __bf16* __restrict__ Keff,
    const __bf16* __restrict__ vT,
    __bf16* __restrict__ ctx)
{
    __shared__ __bf16 Ks[2][64][128];  // 32 KB
    __shared__ __bf16 Vs[2][128][64];  // 32 KB
    __shared__ __bf16 Pl[4][16][72];   // 9.2 KB, row stride 144B
    const int lane = threadIdx.x & 63;
    const int wid  = threadIdx.x >> 6;
    const int r16  = lane & 15;
    const int g    = lane >> 4;
    const int bid  = blockIdx.x;
    const int gidx = ((bid >> 7) << 3) | (bid & 7);
    const int h = gidx & 15, b = gidx >> 4;
    const int p = (bid >> 3) & 15;
    const int nkt = 32 - p;
    const int qbase[2] = { p * 64 + wid * 16, (31 - p) * 64 + wid * 16 };

    bf16x8 aQ[2][4];
    #pragma unroll
    for (int st = 0; st < 2; ++st) {
        const __bf16* qp = xb + ((long)(b * 2048 + qbase[st] + r16)) * 2048 + h * 128 + g * 8;
        #pragma unroll
        for (int ks = 0; ks < 4; ++ks)
            aQ[st][ks] = *reinterpret_cast<const bf16x8*>(qp + ks * 32);
    }

    f32x4 o[2][8];
    float mrow[2], lrow[2];
    #pragma unroll
    for (int st = 0; st < 2; ++st) {
        #pragma unroll
        for (int d8 = 0; d8 < 8; ++d8) o[st][d8] = (f32x4){0.f, 0.f, 0.f, 0.f};
        mrow[st] = -__builtin_inff(); lrow[st] = 0.f;
    }

    const __bf16* Kb = Keff + (long)h * (4096 * 128) + (long)b * (2048 * 128);
    const __bf16* Vb = vT + (long)h * (128 * 4096) + b * 2048;

    const int ksrow = wid * 4 + (lane >> 4);   // + c*16
    const int kslot = lane & 15;
    const int vsrow = wid * 8 + (lane >> 3);   // + c*32
    const int vslot = lane & 7;

    auto stage = [&](int kt, int buf) {
        const int k0s = kt * 64;
        #pragma unroll
        for (int c = 0; c < 4; ++c) {
            const int row = c * 16 + ksrow;
            const int gcol = ((kslot ^ (row & 15)) << 3);
            gload_lds16(&Kb[(long)(k0s + row) * 128 + gcol], &Ks[buf][c * 16 + wid * 4][0]);
        }
        #pragma unroll
        for (int c = 0; c < 4; ++c) {
            const int row = c * 32 + vsrow;
            const int gcol = ((vslot ^ (row & 7)) << 3);
            gload_lds16(&Vb[(long)row * 4096 + k0s + gcol], &Vs[buf][c * 32 + wid * 8][0]);
        }
    };

    const float THR = 11.541560327f;   // 8 * log2(e)
    stage(0, 0);
    for (int kt = 0; kt < nkt; ++kt) {
        const int cur = kt & 1;
        const int k0 = kt * 64;
        __syncthreads();                         // drains vmcnt: buf[cur] ready
        if (kt + 1 < nkt) stage(kt + 1, cur ^ 1);  // prefetch overlaps compute below
        const char* Kbase = reinterpret_cast<const char*>(&Ks[cur][0][0]);
        const char* Vbase = reinterpret_cast<const char*>(&Vs[cur][0][0]);
        const bool light = (kt <= p);

        // QK^T swapped; K-frags read once, feed both streams
        f32x4 sT[2][4];
        #pragma unroll
        for (int kh = 0; kh < 4; ++kh) {
            sT[0][kh] = (f32x4){0.f, 0.f, 0.f, 0.f};
            sT[1][kh] = (f32x4){0.f, 0.f, 0.f, 0.f};
        }
        __builtin_amdgcn_s_setprio(1);
        #pragma unroll
        for (int kh = 0; kh < 4; ++kh) {
            const int krow = kh * 16 + r16;
            bf16x8 bk[4];
            #pragma unroll
            for (int ks = 0; ks < 4; ++ks)
                bk[ks] = *reinterpret_cast<const bf16x8*>(
                    Kbase + krow * 256 + (((ks * 4 + g) ^ (krow & 15)) * 16));
            #pragma unroll
            for (int ks = 0; ks < 4; ++ks)
                sT[1][kh] = __builtin_amdgcn_mfma_f32_16x16x32_bf16(bk[ks], aQ[1][ks], sT[1][kh], 0, 0, 0);
            if (light) {
                #pragma unroll
                for (int ks = 0; ks < 4; ++ks)
                    sT[0][kh] = __builtin_amdgcn_mfma_f32_16x16x32_bf16(bk[ks], aQ[0][ks], sT[0][kh], 0, 0, 0);
            }
        }
        __builtin_amdgcn_s_setprio(0);

        // per-stream softmax (in-place on sT) -> Pl roundtrip -> pa frags
        bf16x8 pa[2][2];
        #pragma unroll
        for (int sti = 0; sti < 2; ++sti) {
            const int st = 1 - sti;              // stream 1 first
            if (st == 0 && !light) continue;
            const bool diag = (st == 0) ? (kt == p) : (kt == nkt - 1);
            if (diag) {
                const int qabs = qbase[st] + r16;
                #pragma unroll
                for (int kh = 0; kh < 4; ++kh)
                    #pragma unroll
                    for (int j = 0; j < 4; ++j)
                        if (k0 + kh * 16 + g * 4 + j > qabs) sT[st][kh][j] = -1e30f;
            }
            float t01 = fmaxf(sT[st][0][0], sT[st][0][1]), t23 = fmaxf(sT[st][0][2], sT[st][0][3]);
            float t45 = fmaxf(sT[st][1][0], sT[st][1][1]), t67 = fmaxf(sT[st][1][2], sT[st][1][3]);
            float t89 = fmaxf(sT[st][2][0], sT[st][2][1]), tab = fmaxf(sT[st][2][2], sT[st][2][3]);
            float tcd = fmaxf(sT[st][3][0], sT[st][3][1]), tef = fmaxf(sT[st][3][2], sT[st][3][3]);
            float tmax = fmaxf(fmaxf(fmaxf(t01, t23), fmaxf(t45, t67)),
                               fmaxf(fmaxf(t89, tab), fmaxf(tcd, tef)));
            tmax = fmaxf(tmax, __shfl_xor(tmax, 16));
            tmax = fmaxf(tmax, __shfl_xor(tmax, 32));
            const int needi = !__all(tmax <= mrow[st] + THR);
            float m = mrow[st], alpha = 1.f;
            if (needi) {
                const float mnew = fmaxf(m, tmax);
                alpha = __builtin_amdgcn_exp2f(m - mnew);   // exp2(-inf)=0 first tile
                m = mnew; mrow[st] = mnew;
            }
            float rsum = 0.f;
            bf16x4 pb[4];
            #pragma unroll
            for (int kh = 0; kh < 4; ++kh) {
                #pragma unroll
                for (int j = 0; j < 4; ++j) {
                    const float pv = __builtin_amdgcn_exp2f(sT[st][kh][j] - m);
                    rsum += pv;
                    pb[kh][j] = (__bf16)pv;
                }
            }
            rsum += __shfl_xor(rsum, 16);
            rsum += __shfl_xor(rsum, 32);
            lrow[st] = lrow[st] * alpha + rsum;
            #pragma unroll
            for (int kh = 0; kh < 4; ++kh)
                *reinterpret_cast<bf16x4*>(&Pl[wid][r16][kh * 16 + g * 4]) = pb[kh];
            pa[st][0] = *reinterpret_cast<const bf16x8*>(&Pl[wid][r16][g * 8]);
            pa[st][1] = *reinterpret_cast<const bf16x8*>(&Pl[wid][r16][32 + g * 8]);
            if (needi) {
                float a4[4];
                #pragma unroll
                for (int j = 0; j < 4; ++j) a4[j] = __shfl(alpha, g * 4 + j);
                #pragma unroll
                for (int d8 = 0; d8 < 8; ++d8) {
                    o[st][d8][0] *= a4[0]; o[st][d8][1] *= a4[1];
                    o[st][d8][2] *= a4[2]; o[st][d8][3] *= a4[3];
                }
            }
        }

        // PV: V-frags read once from LDS, feed both streams
        __builtin_amdgcn_s_setprio(1);
        #pragma unroll
        for (int kk = 0; kk < 2; ++kk) {
            #pragma unroll
            for (int d8 = 0; d8 < 8; ++d8) {
                const int vrow = d8 * 16 + r16;
                bf16x8 bv = *reinterpret_cast<const bf16x8*>(
                    Vbase + vrow * 128 + (((kk * 4 + g) ^ (vrow & 7)) * 16));
                o[1][d8] = __builtin_amdgcn_mfma_f32_16x16x32_bf16(pa[1][kk], bv, o[1][d8], 0, 0, 0);
                if (light)
                    o[0][d8] = __builtin_amdgcn_mfma_f32_16x16x32_bf16(pa[0][kk], bv, o[0][d8], 0, 0, 0);
            }
        }
        __builtin_amdgcn_s_setprio(0);
    }
    #pragma unroll
    for (int st = 0; st < 2; ++st) {
        float rl4[4];
        #pragma unroll
        for (int j = 0; j < 4; ++j) rl4[j] = 1.0f / __shfl(lrow[st], g * 4 + j);
        #pragma unroll
        for (int d8 = 0; d8 < 8; ++d8) {
            #pragma unroll
            for (int j = 0; j < 4; ++j) {
                const int row = qbase[st] + g * 4 + j;
                ctx[((long)(b * 2048 + row)) * 2048 + h * 128 + d8 * 16 + r16] =
                    (__bf16)(o[st][d8][j] * rl4[j]);
            }
        }
    }
}

extern "C" void kernel_launch(void* const* d_in, const int* in_sizes, int n_in,
                              void* d_out, int out_size, void* d_ws, size_t ws_size,
                              hipStream_t stream) {
    const float* x     = (const float*)d_in[0];
    const float* W_q   = (const float*)d_in[1];
    const float* Wd_kv = (const float*)d_in[2];
    const float* W_uv  = (const float*)d_in[3];
    const float* W_uk  = (const float*)d_in[4];
    const float* W_o   = (const float*)d_in[5];
    const float* gamma = (const float*)d_in[6];
    const float* beta  = (const float*)d_in[7];
    float* out     = (float*)d_out;             // [2,2048,2048]
    float* ckv_out = out + 8388608;             // [2,2048,512]

    // workspace layout (bytes), total 100 MB
    char* ws = (char*)d_ws;
    __bf16* xb     = (__bf16*)(ws + 0);           // 16 MB  x bf16 [4096][2048]
    __bf16* Wqb    = (__bf16*)(ws + 16777216);    //  8 MB
    __bf16* Wdkvb  = (__bf16*)(ws + 25165824);    //  2 MB
    __bf16* Wuvb   = (__bf16*)(ws + 27262976);    //  2 MB
    __bf16* Wob    = (__bf16*)(ws + 29360128);    //  8 MB
    __bf16* WukT   = (__bf16*)(ws + 37748736);    //  2 MB  [512][2048]
    __bf16* absk   = (__bf16*)(ws + 39845888);    //  2 MB  absorbed_k [2048][512] (pre-scaled)
    float*  ckvpre = (float*) (ws + 41943040);    //  8 MB  pre-LN [4096][512] f32
    __bf16* ckvb   = (__bf16*)(ws + 50331648);    //  4 MB  c_kv bf16 [4096][512]
    __bf16* Keff   = (__bf16*)(ws + 54525952);    // 16 MB  [16][4096][128]
    __bf16* vT     = (__bf16*)(ws + 71303168);    // 16 MB  [2048][4096]
    __bf16* ctx    = (__bf16*)(ws + 88080384);    // 16 MB  [4096][2048]

    // fused casts + transpose (one launch)
    k_prep<<<9472, 256, 0, stream>>>(x, W_q, Wd_kv, W_uv, W_o, W_uk,
                                     xb, Wqb, Wdkvb, Wuvb, Wob, WukT);

    // scores scale folded into absorbed_k: log2(e)/sqrt(128)
    const float cscale = 1.4426950408889634f * 0.08838834764831845f;
    // merged G1 (absk, bf16, scaled) + G2 (ckvpre, f32): 384 blocks
    k_gemm_g12<<<384, 256, 0, stream>>>(Wqb, WukT, absk, xb, Wdkvb, ckvpre, cscale);
    // LN -> c_kv f32 (output 1) + bf16
    k_layernorm<<<1024, 256, 0, stream>>>(ckvpre, gamma, beta, ckv_out, ckvb);
    // merged G3 (Keff) + G4 (vT): 1024 blocks
    k_gemm_g34<<<1024, 256, 0, stream>>>(ckvb, absk, Keff, Wuvb, vT);
    // attention -> ctx bf16 [4096][2048]  (XCD-grouped 1-D grid)
    k_attn<<<512, 256, 0, stream>>>(xb, Keff, vT, ctx);
    // G5: out[4096][2048] = ctx * W_o^T  (f32 to d_out)
    k_gemm_g5<<<dim3(32, 16), 256, 0, stream>>>(ctx, Wob, out);
}

// Round 12
// 193.932 us; speedup vs baseline: 1.2455x; 1.0387x over previous
//
#include <hip/hip_runtime.h>
#include <hip/hip_bf16.h>
#include <cstdint>

// RopelessMLA forward, MI355X/gfx950.
// B=2, S=2048, D=2048, H=16, DH=128, L=512. Outputs: out [2,2048,2048] f32, c_kv [2,2048,512] f32.
//
// FINAL = round-8 configuration (best measured: 193.9us total, attn 77us 3x reproduced).
// Restructuring:
//   K_eff[h,t,dh] = sum_l c_kv[t,l] * absorbed_k[h,dh,l]   (absorb into keys, QK^T K-dim = 128)
//   scores (log2-domain): absorbed_k pre-scaled by log2(e)/sqrt(128), exp -> exp2
//   vT[h*128+dh][t] = sum_l W_uv[h*128+dh, l] * c_kv[t,l]  (transposed for PV B-frags)
// Attention: 4 waves x (16+16) q-rows, causal-paired q-tiles (p,31-p), XCD-grouped
// grid, K+V dbuf LDS shared across streams, swapped QK^T, log2 softmax, defer-max,
// diag-only mask, setprio, launch_bounds(256,2).
// REFUTED experiments: V-direct-global (R7: 145us), 2-wave/32-row (R9: 127us),
// launch_bounds(256,3) (R6: spill), 8-wave shared staging (R11: correctness fail),
// G3+G4 merge (R10: +7.5us).

typedef __bf16 bf16x8 __attribute__((ext_vector_type(8)));
typedef __bf16 bf16x4 __attribute__((ext_vector_type(4)));
typedef float  f32x4  __attribute__((ext_vector_type(4)));

#define GLOBAL_AS __attribute__((address_space(1)))
#define LDS_AS    __attribute__((address_space(3)))

__device__ __forceinline__ void gload_lds16(const void* g, void* l) {
    __builtin_amdgcn_global_load_lds((const GLOBAL_AS uint32_t*)g,
                                     (LDS_AS uint32_t*)l, 16, 0, 0);
}

// ---------------- fused prep: f32->bf16 casts (5 tensors) + W_uk transpose ----------------
__global__ void k_prep(const float* __restrict__ x, const float* __restrict__ wq,
                       const float* __restrict__ wdkv, const float* __restrict__ wuv,
                       const float* __restrict__ wo, const float* __restrict__ wuk,
                       __bf16* __restrict__ xb, __bf16* __restrict__ wqb,
                       __bf16* __restrict__ wdkvb, __bf16* __restrict__ wuvb,
                       __bf16* __restrict__ wob, __bf16* __restrict__ wukT) {
    __shared__ float t[64][65];
    const int bidx = blockIdx.x;
    if (bidx < 9216) {
        long i = (long)bidx * blockDim.x + threadIdx.x;  // 8-elem group id
        const float* src; __bf16* dst; long off;
        if (i < 1048576)      { src = x;    dst = xb;    off = i; }
        else if (i < 1572864) { src = wq;   dst = wqb;   off = i - 1048576; }
        else if (i < 1703936) { src = wdkv; dst = wdkvb; off = i - 1572864; }
        else if (i < 1835008) { src = wuv;  dst = wuvb;  off = i - 1703936; }
        else                  { src = wo;   dst = wob;   off = i - 1835008; }
        long e = off * 8;
        float4 a = *reinterpret_cast<const float4*>(src + e);
        float4 b = *reinterpret_cast<const float4*>(src + e + 4);
        bf16x8 r;
        r[0] = (__bf16)a.x; r[1] = (__bf16)a.y; r[2] = (__bf16)a.z; r[3] = (__bf16)a.w;
        r[4] = (__bf16)b.x; r[5] = (__bf16)b.y; r[6] = (__bf16)b.z; r[7] = (__bf16)b.w;
        *reinterpret_cast<bf16x8*>(dst + e) = r;
    } else {
        const int tb = bidx - 9216;                 // 256 blocks
        const int d0 = (tb & 31) * 64, l0 = (tb >> 5) * 64;
        const int tid = threadIdx.x;
        const int r = tid >> 4, c = (tid & 15) * 4;
        #pragma unroll
        for (int rr = 0; rr < 64; rr += 16) {
            float4 v = *reinterpret_cast<const float4*>(&wuk[(long)(d0 + r + rr) * 512 + l0 + c]);
            t[r + rr][c] = v.x; t[r + rr][c + 1] = v.y;
            t[r + rr][c + 2] = v.z; t[r + rr][c + 3] = v.w;
        }
        __syncthreads();
        const int lr = tid >> 2, dc = (tid & 3) * 16;
        bf16x8 o0, o1;
        #pragma unroll
        for (int i = 0; i < 8; ++i) { o0[i] = (__bf16)t[dc + i][lr]; o1[i] = (__bf16)t[dc + 8 + i][lr]; }
        *reinterpret_cast<bf16x8*>(&wukT[(long)(l0 + lr) * 2048 + d0 + dc]) = o0;
        *reinterpret_cast<bf16x8*>(&wukT[(long)(l0 + lr) * 2048 + d0 + dc + 8]) = o1;
    }
}

// ---------------- merged G1+G2 (both M x 512 = A[M][2048] * B[512][2048]^T) ----------------
// blocks [0,128): G1 absk[2048][512] = cscale * Wqb * WukT^T  (bf16 out)
// blocks [128,384): G2 ckvpre[4096][512] = xb * Wdkvb^T       (f32 out)
__global__ __launch_bounds__(256, 2) void k_gemm_g12(
    const __bf16* __restrict__ Wqb, const __bf16* __restrict__ WukT, __bf16* __restrict__ absk,
    const __bf16* __restrict__ xb, const __bf16* __restrict__ Wdkvb, float* __restrict__ ckvpre,
    float cscale)
{
    __shared__ __bf16 Asm[128][64];
    __shared__ __bf16 Bsm[64][64];
    const int bid = blockIdx.x;
    const bool g1s = (bid < 128);
    const int lbid = g1s ? bid : bid - 128;
    const int tm = (lbid >> 3) * 128, tn = (lbid & 7) * 64;
    const __bf16* A = g1s ? Wqb : xb;
    const __bf16* B = g1s ? WukT : Wdkvb;
    const int tid  = threadIdx.x;
    const int lane = tid & 63, wid = tid >> 6;
    const int r16 = lane & 15, g = lane >> 4;
    const int srow  = lane >> 3;
    const int sslot = lane & 7;
    const int scol  = ((sslot ^ srow) * 8);

    f32x4 acc[2][4];
    #pragma unroll
    for (int m = 0; m < 2; ++m)
        #pragma unroll
        for (int n = 0; n < 4; ++n) acc[m][n] = (f32x4){0.f, 0.f, 0.f, 0.f};

    for (int kt = 0; kt < 2048; kt += 64) {
        __syncthreads();
        #pragma unroll
        for (int c2 = 0; c2 < 4; ++c2) {
            const int chunk = wid * 4 + c2;
            const int row   = chunk * 8 + srow;
            gload_lds16(&A[(long)(tm + row) * 2048 + kt + scol], &Asm[chunk * 8][0]);
        }
        #pragma unroll
        for (int c2 = 0; c2 < 2; ++c2) {
            const int chunk = wid * 2 + c2;
            const int row   = chunk * 8 + srow;
            gload_lds16(&B[(long)(tn + row) * 2048 + kt + scol], &Bsm[chunk * 8][0]);
        }
        __syncthreads();
        #pragma unroll
        for (int kk = 0; kk < 2; ++kk) {
            bf16x8 af[2], bfr[4];
            #pragma unroll
            for (int m = 0; m < 2; ++m) {
                const int row = wid * 32 + m * 16 + r16;
                af[m] = *reinterpret_cast<const bf16x8*>(
                    reinterpret_cast<const char*>(&Asm[0][0]) +
                    row * 128 + (((kk * 4 + g) ^ (row & 7)) * 16));
            }
            #pragma unroll
            for (int n = 0; n < 4; ++n) {
                const int row = n * 16 + r16;
                bfr[n] = *reinterpret_cast<const bf16x8*>(
                    reinterpret_cast<const char*>(&Bsm[0][0]) +
                    row * 128 + (((kk * 4 + g) ^ (row & 7)) * 16));
            }
            #pragma unroll
            for (int m = 0; m < 2; ++m)
                #pragma unroll
                for (int n = 0; n < 4; ++n)
                    acc[m][n] = __builtin_amdgcn_mfma_f32_16x16x32_bf16(af[m], bfr[n], acc[m][n], 0, 0, 0);
        }
    }
    #pragma unroll
    for (int m = 0; m < 2; ++m) {
        #pragma unroll
        for (int n = 0; n < 4; ++n) {
            #pragma unroll
            for (int j = 0; j < 4; ++j) {
                const int row = tm + wid * 32 + m * 16 + g * 4 + j;
                const int col = tn + n * 16 + r16;
                if (g1s) absk[(long)row * 512 + col] = (__bf16)(acc[m][n][j] * cscale);
                else     ckvpre[(long)row * 512 + col] = acc[m][n][j];
            }
        }
    }
}

// ---------------- generic bf16 GEMM, C = cmul * (A * B^T) ----------------
// A [M][K] (lda), B [N][K] (ldb), C [M][N] (ldc). BM=128, BN=128, 2x2 waves.
// LDS XOR-swizzle on both staging source and ds_read (rule #21).
template <typename CT>
__global__ __launch_bounds__(256, 2) void k_gemm_bt(
    const __bf16* __restrict__ A, const __bf16* __restrict__ B, CT* __restrict__ C,
    int K, int lda, int ldb, int ldc,
    long aOffZ, long bOffZ, long cOffZ, float cmul)
{
    A += (long)blockIdx.z * aOffZ;
    B += (long)blockIdx.z * bOffZ;
    C += (long)blockIdx.z * cOffZ;
    __shared__ __bf16 Asm[128][64];
    __shared__ __bf16 Bsm[128][64];
    const int tid  = threadIdx.x;
    const int lane = tid & 63, wid = tid >> 6;
    const int wr = wid >> 1, wc = wid & 1;
    const int tm = blockIdx.x * 128, tn = blockIdx.y * 128;
    const int r16 = lane & 15, g = lane >> 4;

    const int srow  = lane >> 3;
    const int sslot = lane & 7;
    const int scol  = ((sslot ^ srow) * 8);

    f32x4 acc[4][4];
    #pragma unroll
    for (int m = 0; m < 4; ++m)
        #pragma unroll
        for (int n = 0; n < 4; ++n) acc[m][n] = (f32x4){0.f, 0.f, 0.f, 0.f};

    for (int kt = 0; kt < K; kt += 64) {
        __syncthreads();
        #pragma unroll
        for (int c2 = 0; c2 < 4; ++c2) {
            const int chunk = wid * 4 + c2;
            const int row   = chunk * 8 + srow;
            gload_lds16(&A[(long)(tm + row) * lda + kt + scol], &Asm[chunk * 8][0]);
            gload_lds16(&B[(long)(tn + row) * ldb + kt + scol], &Bsm[chunk * 8][0]);
        }
        __syncthreads();
        #pragma unroll
        for (int kk = 0; kk < 2; ++kk) {
            bf16x8 af[4], bfr[4];
            #pragma unroll
            for (int m = 0; m < 4; ++m) {
                const int row = wr * 64 + m * 16 + r16;
                af[m] = *reinterpret_cast<const bf16x8*>(
                    reinterpret_cast<const char*>(&Asm[0][0]) +
                    row * 128 + (((kk * 4 + g) ^ (row & 7)) * 16));
            }
            #pragma unroll
            for (int n = 0; n < 4; ++n) {
                const int row = wc * 64 + n * 16 + r16;
                bfr[n] = *reinterpret_cast<const bf16x8*>(
                    reinterpret_cast<const char*>(&Bsm[0][0]) +
                    row * 128 + (((kk * 4 + g) ^ (row & 7)) * 16));
            }
            #pragma unroll
            for (int m = 0; m < 4; ++m)
                #pragma unroll
                for (int n = 0; n < 4; ++n)
                    acc[m][n] = __builtin_amdgcn_mfma_f32_16x16x32_bf16(af[m], bfr[n], acc[m][n], 0, 0, 0);
        }
    }
    #pragma unroll
    for (int m = 0; m < 4; ++m) {
        #pragma unroll
        for (int n = 0; n < 4; ++n) {
            #pragma unroll
            for (int j = 0; j < 4; ++j) {
                const int row = tm + wr * 64 + m * 16 + g * 4 + j;
                const int col = tn + wc * 64 + n * 16 + r16;
                C[(long)row * ldc + col] = (CT)(acc[m][n][j] * cmul);
            }
        }
    }
}

// ---------------- LayerNorm over L=512, one wave per row ----------------
__global__ void k_layernorm(const float* __restrict__ pre, const float* __restrict__ gamma,
                            const float* __restrict__ beta, float* __restrict__ out_f32,
                            __bf16* __restrict__ out_bf16) {
    const int row  = blockIdx.x * 4 + (threadIdx.x >> 6);
    const int lane = threadIdx.x & 63;
    const float* p = pre + (long)row * 512;
    float4 v0 = *reinterpret_cast<const float4*>(p + lane * 4);
    float4 v1 = *reinterpret_cast<const float4*>(p + 256 + lane * 4);
    float s  = v0.x + v0.y + v0.z + v0.w + v1.x + v1.y + v1.z + v1.w;
    float s2 = v0.x*v0.x + v0.y*v0.y + v0.z*v0.z + v0.w*v0.w
             + v1.x*v1.x + v1.y*v1.y + v1.z*v1.z + v1.w*v1.w;
    #pragma unroll
    for (int d = 1; d < 64; d <<= 1) { s += __shfl_xor(s, d); s2 += __shfl_xor(s2, d); }
    const float mu  = s * (1.0f / 512.0f);
    const float var = s2 * (1.0f / 512.0f) - mu * mu;
    const float rs  = rsqrtf(var + 1e-5f);
    float4 g0 = *reinterpret_cast<const float4*>(gamma + lane * 4);
    float4 g1 = *reinterpret_cast<const float4*>(gamma + 256 + lane * 4);
    float4 b0 = *reinterpret_cast<const float4*>(beta + lane * 4);
    float4 b1 = *reinterpret_cast<const float4*>(beta + 256 + lane * 4);
    float4 y0, y1;
    y0.x = (v0.x - mu) * rs * g0.x + b0.x;  y0.y = (v0.y - mu) * rs * g0.y + b0.y;
    y0.z = (v0.z - mu) * rs * g0.z + b0.z;  y0.w = (v0.w - mu) * rs * g0.w + b0.w;
    y1.x = (v1.x - mu) * rs * g1.x + b1.x;  y1.y = (v1.y - mu) * rs * g1.y + b1.y;
    y1.z = (v1.z - mu) * rs * g1.z + b1.z;  y1.w = (v1.w - mu) * rs * g1.w + b1.w;
    *reinterpret_cast<float4*>(out_f32 + (long)row * 512 + lane * 4) = y0;
    *reinterpret_cast<float4*>(out_f32 + (long)row * 512 + 256 + lane * 4) = y1;
    bf16x4 z0, z1;
    z0[0] = (__bf16)y0.x; z0[1] = (__bf16)y0.y; z0[2] = (__bf16)y0.z; z0[3] = (__bf16)y0.w;
    z1[0] = (__bf16)y1.x; z1[1] = (__bf16)y1.y; z1[2] = (__bf16)y1.z; z1[3] = (__bf16)y1.w;
    *reinterpret_cast<bf16x4*>(out_bf16 + (long)row * 512 + lane * 4) = z0;
    *reinterpret_cast<bf16x4*>(out_bf16 + (long)row * 512 + 256 + lane * 4) = z1;
}

// ---------------- causal flash attention (round-8 config, measured 77us) ----------------
// 1-D grid of 512 blocks, XCD-grouped: same (h,b) -> same bid&7. Block p owns
// q-tiles {p, 31-p}. K and V staged once into dbuf LDS; K/V LDS fragment reads
// shared across both streams; Pl reused sequentially per stream.
__global__ __launch_bounds__(256, 2) void k_attn(
    const __bf16* __restrict__ xb,
    const __bf16* __restrict__ Keff,
    const __bf16* __restrict__ vT,
    __bf16* __restrict__ ctx)
{
    __shared__ __bf16 Ks[2][64][128];  // 32 KB
    __shared__ __bf16 Vs[2][128][64];  // 32 KB
    __shared__ __bf16 Pl[4][16][72];   // 9.2 KB, row stride 144B
    const int lane = threadIdx.x & 63;
    const int wid  = threadIdx.x >> 6;
    const int r16  = lane & 15;
    const int g    = lane >> 4;
    const int bid  = blockIdx.x;
    const int gidx = ((bid >> 7) << 3) | (bid & 7);
    const int h = gidx & 15, b = gidx >> 4;
    const int p = (bid >> 3) & 15;
    const int nkt = 32 - p;
    const int qbase[2] = { p * 64 + wid * 16, (31 - p) * 64 + wid * 16 };

    bf16x8 aQ[2][4];
    #pragma unroll
    for (int st = 0; st < 2; ++st) {
        const __bf16* qp = xb + ((long)(b * 2048 + qbase[st] + r16)) * 2048 + h * 128 + g * 8;
        #pragma unroll
        for (int ks = 0; ks < 4; ++ks)
            aQ[st][ks] = *reinterpret_cast<const bf16x8*>(qp + ks * 32);
    }

    f32x4 o[2][8];
    float mrow[2], lrow[2];
    #pragma unroll
    for (int st = 0; st < 2; ++st) {
        #pragma unroll
        for (int d8 = 0; d8 < 8; ++d8) o[st][d8] = (f32x4){0.f, 0.f, 0.f, 0.f};
        mrow[st] = -__builtin_inff(); lrow[st] = 0.f;
    }

    const __bf16* Kb = Keff + (long)h * (4096 * 128) + (long)b * (2048 * 128);
    const __bf16* Vb = vT + (long)h * (128 * 4096) + b * 2048;

    const int ksrow = wid * 4 + (lane >> 4);   // + c*16
    const int kslot = lane & 15;
    const int vsrow = wid * 8 + (lane >> 3);   // + c*32
    const int vslot = lane & 7;

    auto stage = [&](int kt, int buf) {
        const int k0s = kt * 64;
        #pragma unroll
        for (int c = 0; c < 4; ++c) {
            const int row = c * 16 + ksrow;
            const int gcol = ((kslot ^ (row & 15)) << 3);
            gload_lds16(&Kb[(long)(k0s + row) * 128 + gcol], &Ks[buf][c * 16 + wid * 4][0]);
        }
        #pragma unroll
        for (int c = 0; c < 4; ++c) {
            const int row = c * 32 + vsrow;
            const int gcol = ((vslot ^ (row & 7)) << 3);
            gload_lds16(&Vb[(long)row * 4096 + k0s + gcol], &Vs[buf][c * 32 + wid * 8][0]);
        }
    };

    const float THR = 11.541560327f;   // 8 * log2(e)
    stage(0, 0);
    for (int kt = 0; kt < nkt; ++kt) {
        const int cur = kt & 1;
        const int k0 = kt * 64;
        __syncthreads();                         // drains vmcnt: buf[cur] ready
        if (kt + 1 < nkt) stage(kt + 1, cur ^ 1);  // prefetch overlaps compute below
        const char* Kbase = reinterpret_cast<const char*>(&Ks[cur][0][0]);
        const char* Vbase = reinterpret_cast<const char*>(&Vs[cur][0][0]);
        const bool light = (kt <= p);

        // QK^T swapped; K-frags read once, feed both streams
        f32x4 sT[2][4];
        #pragma unroll
        for (int kh = 0; kh < 4; ++kh) {
            sT[0][kh] = (f32x4){0.f, 0.f, 0.f, 0.f};
            sT[1][kh] = (f32x4){0.f, 0.f, 0.f, 0.f};
        }
        __builtin_amdgcn_s_setprio(1);
        #pragma unroll
        for (int kh = 0; kh < 4; ++kh) {
            const int krow = kh * 16 + r16;
            bf16x8 bk[4];
            #pragma unroll
            for (int ks = 0; ks < 4; ++ks)
                bk[ks] = *reinterpret_cast<const bf16x8*>(
                    Kbase + krow * 256 + (((ks * 4 + g) ^ (krow & 15)) * 16));
            #pragma unroll
            for (int ks = 0; ks < 4; ++ks)
                sT[1][kh] = __builtin_amdgcn_mfma_f32_16x16x32_bf16(bk[ks], aQ[1][ks], sT[1][kh], 0, 0, 0);
            if (light) {
                #pragma unroll
                for (int ks = 0; ks < 4; ++ks)
                    sT[0][kh] = __builtin_amdgcn_mfma_f32_16x16x32_bf16(bk[ks], aQ[0][ks], sT[0][kh], 0, 0, 0);
            }
        }
        __builtin_amdgcn_s_setprio(0);

        // per-stream softmax (in-place on sT) -> Pl roundtrip -> pa frags
        bf16x8 pa[2][2];
        #pragma unroll
        for (int sti = 0; sti < 2; ++sti) {
            const int st = 1 - sti;              // stream 1 first
            if (st == 0 && !light) continue;
            const bool diag = (st == 0) ? (kt == p) : (kt == nkt - 1);
            if (diag) {
                const int qabs = qbase[st] + r16;
                #pragma unroll
                for (int kh = 0; kh < 4; ++kh)
                    #pragma unroll
                    for (int j = 0; j < 4; ++j)
                        if (k0 + kh * 16 + g * 4 + j > qabs) sT[st][kh][j] = -1e30f;
            }
            float t01 = fmaxf(sT[st][0][0], sT[st][0][1]), t23 = fmaxf(sT[st][0][2], sT[st][0][3]);
            float t45 = fmaxf(sT[st][1][0], sT[st][1][1]), t67 = fmaxf(sT[st][1][2], sT[st][1][3]);
            float t89 = fmaxf(sT[st][2][0], sT[st][2][1]), tab = fmaxf(sT[st][2][2], sT[st][2][3]);
            float tcd = fmaxf(sT[st][3][0], sT[st][3][1]), tef = fmaxf(sT[st][3][2], sT[st][3][3]);
            float tmax = fmaxf(fmaxf(fmaxf(t01, t23), fmaxf(t45, t67)),
                               fmaxf(fmaxf(t89, tab), fmaxf(tcd, tef)));
            tmax = fmaxf(tmax, __shfl_xor(tmax, 16));
            tmax = fmaxf(tmax, __shfl_xor(tmax, 32));
            const int needi = !__all(tmax <= mrow[st] + THR);
            float m = mrow[st], alpha = 1.f;
            if (needi) {
                const float mnew = fmaxf(m, tmax);
                alpha = __builtin_amdgcn_exp2f(m - mnew);   // exp2(-inf)=0 first tile
                m = mnew; mrow[st] = mnew;
            }
            float rsum = 0.f;
            bf16x4 pb[4];
            #pragma unroll
            for (int kh = 0; kh < 4; ++kh) {
                #pragma unroll
                for (int j = 0; j < 4; ++j) {
                    const float pv = __builtin_amdgcn_exp2f(sT[st][kh][j] - m);
                    rsum += pv;
                    pb[kh][j] = (__bf16)pv;
                }
            }
            rsum += __shfl_xor(rsum, 16);
            rsum += __shfl_xor(rsum, 32);
            lrow[st] = lrow[st] * alpha + rsum;
            #pragma unroll
            for (int kh = 0; kh < 4; ++kh)
                *reinterpret_cast<bf16x4*>(&Pl[wid][r16][kh * 16 + g * 4]) = pb[kh];
            pa[st][0] = *reinterpret_cast<const bf16x8*>(&Pl[wid][r16][g * 8]);
            pa[st][1] = *reinterpret_cast<const bf16x8*>(&Pl[wid][r16][32 + g * 8]);
            if (needi) {
                float a4[4];
                #pragma unroll
                for (int j = 0; j < 4; ++j) a4[j] = __shfl(alpha, g * 4 + j);
                #pragma unroll
                for (int d8 = 0; d8 < 8; ++d8) {
                    o[st][d8][0] *= a4[0]; o[st][d8][1] *= a4[1];
                    o[st][d8][2] *= a4[2]; o[st][d8][3] *= a4[3];
                }
            }
        }

        // PV: V-frags read once from LDS, feed both streams
        __builtin_amdgcn_s_setprio(1);
        #pragma unroll
        for (int kk = 0; kk < 2; ++kk) {
            #pragma unroll
            for (int d8 = 0; d8 < 8; ++d8) {
                const int vrow = d8 * 16 + r16;
                bf16x8 bv = *reinterpret_cast<const bf16x8*>(
                    Vbase + vrow * 128 + (((kk * 4 + g) ^ (vrow & 7)) * 16));
                o[1][d8] = __builtin_amdgcn_mfma_f32_16x16x32_bf16(pa[1][kk], bv, o[1][d8], 0, 0, 0);
                if (light)
                    o[0][d8] = __builtin_amdgcn_mfma_f32_16x16x32_bf16(pa[0][kk], bv, o[0][d8], 0, 0, 0);
            }
        }
        __builtin_amdgcn_s_setprio(0);
    }
    #pragma unroll
    for (int st = 0; st < 2; ++st) {
        float rl4[4];
        #pragma unroll
        for (int j = 0; j < 4; ++j) rl4[j] = 1.0f / __shfl(lrow[st], g * 4 + j);
        #pragma unroll
        for (int d8 = 0; d8 < 8; ++d8) {
            #pragma unroll
            for (int j = 0; j < 4; ++j) {
                const int row = qbase[st] + g * 4 + j;
                ctx[((long)(b * 2048 + row)) * 2048 + h * 128 + d8 * 16 + r16] =
                    (__bf16)(o[st][d8][j] * rl4[j]);
            }
        }
    }
}

extern "C" void kernel_launch(void* const* d_in, const int* in_sizes, int n_in,
                              void* d_out, int out_size, void* d_ws, size_t ws_size,
                              hipStream_t stream) {
    const float* x     = (const float*)d_in[0];
    const float* W_q   = (const float*)d_in[1];
    const float* Wd_kv = (const float*)d_in[2];
    const float* W_uv  = (const float*)d_in[3];
    const float* W_uk  = (const float*)d_in[4];
    const float* W_o   = (const float*)d_in[5];
    const float* gamma = (const float*)d_in[6];
    const float* beta  = (const float*)d_in[7];
    float* out     = (float*)d_out;             // [2,2048,2048]
    float* ckv_out = out + 8388608;             // [2,2048,512]

    // workspace layout (bytes), total 100 MB
    char* ws = (char*)d_ws;
    __bf16* xb     = (__bf16*)(ws + 0);           // 16 MB  x bf16 [4096][2048]
    __bf16* Wqb    = (__bf16*)(ws + 16777216);    //  8 MB
    __bf16* Wdkvb  = (__bf16*)(ws + 25165824);    //  2 MB
    __bf16* Wuvb   = (__bf16*)(ws + 27262976);    //  2 MB
    __bf16* Wob    = (__bf16*)(ws + 29360128);    //  8 MB
    __bf16* WukT   = (__bf16*)(ws + 37748736);    //  2 MB  [512][2048]
    __bf16* absk   = (__bf16*)(ws + 39845888);    //  2 MB  absorbed_k [2048][512] (pre-scaled)
    float*  ckvpre = (float*) (ws + 41943040);    //  8 MB  pre-LN [4096][512] f32
    __bf16* ckvb   = (__bf16*)(ws + 50331648);    //  4 MB  c_kv bf16 [4096][512]
    __bf16* Keff   = (__bf16*)(ws + 54525952);    // 16 MB  [16][4096][128]
    __bf16* vT     = (__bf16*)(ws + 71303168);    // 16 MB  [2048][4096]
    __bf16* ctx    = (__bf16*)(ws + 88080384);    // 16 MB  [4096][2048]

    // fused casts + transpose (one launch)
    k_prep<<<9472, 256, 0, stream>>>(x, W_q, Wd_kv, W_uv, W_o, W_uk,
                                     xb, Wqb, Wdkvb, Wuvb, Wob, WukT);

    // scores scale folded into absorbed_k: log2(e)/sqrt(128)
    const float cscale = 1.4426950408889634f * 0.08838834764831845f;
    // merged G1 (absk, bf16, scaled) + G2 (ckvpre, f32): 384 blocks
    k_gemm_g12<<<384, 256, 0, stream>>>(Wqb, WukT, absk, xb, Wdkvb, ckvpre, cscale);
    // LN -> c_kv f32 (output 1) + bf16
    k_layernorm<<<1024, 256, 0, stream>>>(ckvpre, gamma, beta, ckv_out, ckvb);
    // G3: K_eff[h][4096][128] = c_kv * absorbed_k[h]^T  (grid.z = heads)
    k_gemm_bt<__bf16><<<dim3(32, 1, 16), 256, 0, stream>>>(ckvb, absk, Keff,
        512, 512, 512, 128, 0, 128 * 512, 4096 * 128, 1.0f);
    // G4: vT[2048][4096] = W_uv * c_kv^T   (v_full transposed)
    k_gemm_bt<__bf16><<<dim3(16, 32, 1), 256, 0, stream>>>(Wuvb, ckvb, vT,
        512, 512, 512, 4096, 0, 0, 0, 1.0f);
    // attention -> ctx bf16 [4096][2048]  (XCD-grouped 1-D grid)
    k_attn<<<512, 256, 0, stream>>>(xb, Keff, vT, ctx);
    // G5: out[4096][2048] = ctx * W_o^T  (f32 to d_out)
    k_gemm_bt<float><<<dim3(32, 16, 1), 256, 0, stream>>>(ctx, Wob, out,
        2048, 2048, 2048, 2048, 0, 0, 0, 1.0f);
}